// Round 6
// baseline (356.600 us; speedup 1.0000x reference)
//
#include <hip/hip_runtime.h>
#include <math.h>

// Problem constants
#define IMGS 256
#define NANG 50
#define BATCH 4
#define NCNN 32
#define PIX (IMGS*IMGS)              // 65536
#define NPIX (BATCH*PIX)             // 262144

// Workspace layout (float offsets)
#define OFF_FILT  0          // 51200 filtered sinogram (b,a,s)
#define OFF_W2BF  51200      // 9216 bf16 = 4608 floats ([tap][oc][ic])

static constexpr double PI_D = 3.14159265358979323846;

typedef unsigned short u16;
typedef unsigned int   u32;
typedef unsigned long long u64;
typedef __bf16 bfrag __attribute__((ext_vector_type(8)));
typedef float  ffrag __attribute__((ext_vector_type(4)));

__device__ __forceinline__ u16 f2bf(float f) {
    u32 u = __float_as_uint(f);
    u += 0x7fffu + ((u >> 16) & 1u);     // RNE
    return (u16)(u >> 16);
}

// =========== K_A: radon forward + ramp filter (fused), + w2->bf16 ===========
// (unchanged, proven through rounds 0-5)
#define RPITCH_D 131            // dwords per LDS image row (odd => bank-friendly)
__global__ __launch_bounds__(1024, 4) void k_A(const float* __restrict__ angles,
                                               const float* __restrict__ yprev,
                                               const float* __restrict__ xsino,
                                               const float* __restrict__ w2,
                                               float* __restrict__ ws) {
    __shared__ u16 limg[258 * 262];      // 135,192 B
    __shared__ float spart[1024];
    __shared__ float staps[512];
    __shared__ float srow[256];
    int tid = threadIdx.x;
    int gid = blockIdx.x;
    if (gid >= 200) {                    // w2 conversion blocks
        int i = (gid - 200) * 1024 + tid;
        if (i < 9216) {
            int t = i >> 10, oc = (i >> 5) & 31, ic = i & 31;
            ((u16*)(ws + OFF_W2BF))[i] = f2bf(w2[(oc * 32 + ic) * 9 + t]);
        }
        return;
    }
    u32* l32 = (u32*)limg;
    int ra = gid;                        // b*50 + a
    int a = ra % NANG, b = ra / NANG;

    // ramp taps, closed form
    if (tid < 511) {
        int d = tid - 255;
        int n = d < 0 ? -d : d;
        double g;
        if (n == 0) {
            g = 0.5;
        } else {
            double th = PI_D * (double)n / 256.0;
            double S = (256.0 * cos(255.0 * th) - 255.0 * cos(256.0 * th) - 1.0)
                       / (2.0 * (1.0 - cos(th)));
            double sign = (n & 1) ? -1.0 : 1.0;
            g = (sign + S / 128.0) / 512.0;
        }
        staps[tid] = (float)(g * PI_D / 100.0);   // fold pi/(2A), A=50
    }

    // zero image borders
    for (int z = tid; z < 772; z += 1024) {
        int addr;
        if (z < 258)      addr = z * RPITCH_D;
        else if (z < 516) addr = (z - 258) * RPITCH_D + 129;
        else if (z < 644) addr = (z - 516) + 1;
        else              addr = 257 * RPITCH_D + (z - 644) + 1;
        l32[addr] = 0;
    }
    // stage interior: mask inline, fp32 -> bf16
    const float* __restrict__ src = yprev + b * PIX;
    for (int idx = tid; idx < 16384; idx += 1024) {
        int r = idx >> 6, c4 = (idx & 63) << 2;
        float4 v = *(const float4*)(src + r * 256 + c4);
        float di = (float)r - 127.5f;
        float rr = di * di;
        float d0 = (float)c4 - 127.5f;
        v.x = (rr + d0 * d0 <= 16384.0f) ? v.x : 0.0f;
        v.y = (rr + (d0 + 1.0f) * (d0 + 1.0f) <= 16384.0f) ? v.y : 0.0f;
        v.z = (rr + (d0 + 2.0f) * (d0 + 2.0f) <= 16384.0f) ? v.z : 0.0f;
        v.w = (rr + (d0 + 3.0f) * (d0 + 3.0f) <= 16384.0f) ? v.w : 0.0f;
        u32 p0 = (u32)f2bf(v.x) | ((u32)f2bf(v.y) << 16);
        u32 p1 = (u32)f2bf(v.z) | ((u32)f2bf(v.w) << 16);
        int dw = (r + 1) * RPITCH_D + (c4 >> 1) + 1;
        l32[dw] = p0; l32[dw + 1] = p1;
    }
    __syncthreads();

    float a_ = angles[a];
    float cs = cosf(a_), sn = sinf(a_);
    int lane = tid & 63, w = tid >> 6;   // 16 waves
    int s8 = lane & 7, t8 = lane >> 3;   // 8x8 patch coords
    int sA = w * 16 + s8;                // this thread's two s rows: sA, sA+8
    float scA = (float)sA - 127.5f;

    float loA = (float)(w * 16) - 127.5f, hiA = loA + 7.0f;
    float loB = loA + 8.0f,               hiB = hiA + 8.0f;
    float s2minA = fminf(loA * loA, hiA * hiA);
    float s2maxA = fmaxf(loA * loA, hiA * hiA);
    float s2minB = fminf(loB * loB, hiB * hiB);
    float s2maxB = fmaxf(loB * loB, hiB * hiB);
    float s2min  = fminf(s2minA, s2minB);
    float s2max  = fmaxf(s2maxA, s2maxB);
    float hmax = sqrtf(16770.25f - s2min);                 // 129.5^2
    int j_lo = max(0, (int)ceilf((120.5f - hmax) * 0.125f));
    int j_hi = min(31, (int)floorf((127.5f + hmax) * 0.125f));

    float tc0 = (float)t8 - 127.5f + 8.0f * (float)j_lo;
    float rowA = scA * sn + tc0 * cs + 127.5f;
    float colA = scA * cs - tc0 * sn + 127.5f;
    float rowB = rowA + 8.0f * sn;
    float colB = colA + 8.0f * cs;
    float cs8 = 8.0f * cs, sn8 = 8.0f * sn;
    float accA = 0.0f, accB = 0.0f;
    #pragma unroll 2
    for (int j = j_lo; j <= j_hi; ++j) {   // t = t8 + 8j
        float t0j = 8.0f * (float)j - 127.5f;
        float t7j = t0j + 7.0f;
        float tmax2 = fmaxf(t0j * t0j, t7j * t7j);
        if (s2max + tmax2 <= 16384.0f) {
            #pragma unroll
            for (int hh = 0; hh < 2; ++hh) {
                float rowv = hh ? rowB : rowA;
                float colv = hh ? colB : colA;
                float fr = floorf(rowv), fc = floorf(colv);
                float wr = rowv - fr, wc = colv - fc;
                int i0 = (int)fr, j0 = (int)fc;
                int ca = j0 + 2;
                int ka = ca >> 1;
                int sh = (ca & 1) << 4;
                int dw = (i0 + 1) * RPITCH_D + ka;
                u32 A = l32[dw],            C = l32[dw + 1];
                u32 B = l32[dw + RPITCH_D], D = l32[dw + RPITCH_D + 1];
                u32 top = (u32)((((u64)C << 32) | (u64)A) >> sh);
                u32 bot = (u32)((((u64)D << 32) | (u64)B) >> sh);
                float tl = __uint_as_float(top << 16);
                float tr_ = __uint_as_float(top & 0xffff0000u);
                float bl = __uint_as_float(bot << 16);
                float br = __uint_as_float(bot & 0xffff0000u);
                float tv = tl + (tr_ - tl) * wc;
                float bv = bl + (br - bl) * wc;
                float sv = tv + (bv - tv) * wr;
                if (hh) accB += sv; else accA += sv;
            }
        } else {
            #pragma unroll
            for (int hh = 0; hh < 2; ++hh) {
                float rowv = hh ? rowB : rowA;
                float colv = hh ? colB : colA;
                float fr = floorf(rowv), fc = floorf(colv);
                float wr = rowv - fr, wc = colv - fc;
                int i0 = (int)fr, j0 = (int)fc;
                bool valid = (rowv > -1.0f) & (rowv < 256.0f) & (colv > -1.0f) & (colv < 256.0f);
                int i0c = min(max(i0, -1), 255);
                int j0c = min(max(j0, -1), 255);
                int ca = j0c + 2;
                int ka = ca >> 1;
                int sh = (ca & 1) << 4;
                int dw = (i0c + 1) * RPITCH_D + ka;
                u32 A = l32[dw],            C = l32[dw + 1];
                u32 B = l32[dw + RPITCH_D], D = l32[dw + RPITCH_D + 1];
                u32 top = (u32)((((u64)C << 32) | (u64)A) >> sh);
                u32 bot = (u32)((((u64)D << 32) | (u64)B) >> sh);
                float tl = __uint_as_float(top << 16);
                float tr_ = __uint_as_float(top & 0xffff0000u);
                float bl = __uint_as_float(bot << 16);
                float br = __uint_as_float(bot & 0xffff0000u);
                float tv = tl + (tr_ - tl) * wc;
                float bv = bl + (br - bl) * wc;
                float sv = tv + (bv - tv) * wr;
                sv = valid ? sv : 0.0f;
                if (hh) accB += sv; else accA += sv;
            }
        }
        rowA += cs8; colA -= sn8; rowB += cs8; colB -= sn8;
    }
    accA += __shfl_xor(accA, 8, 64);
    accA += __shfl_xor(accA, 16, 64);
    accA += __shfl_xor(accA, 32, 64);
    accB += __shfl_xor(accB, 8, 64);
    accB += __shfl_xor(accB, 16, 64);
    accB += __shfl_xor(accB, 32, 64);
    if (t8 == 0) { spart[sA] = accA; spart[sA + 8] = accB; }
    __syncthreads();
    if (tid < 256)
        srow[tid] = spart[tid] - xsino[ra * 256 + tid];
    __syncthreads();
    {   // 511-tap filter, split 4 ways over taps
        int s = tid & 255, q = tid >> 8;
        float fa = 0.0f;
        int m0 = q * 64;
        #pragma unroll 8
        for (int m = m0; m < m0 + 64; ++m) fa += srow[m] * staps[s - m + 255];
        spart[tid] = fa;
    }
    __syncthreads();
    if (tid < 256)
        ws[OFF_FILT + ra * 256 + tid] =
            spart[tid] + spart[tid + 256] + spart[tid + 512] + spart[tid + 768];
}

// =========== K_BC v2: fused, x-quartered for 2 blocks/CU =================
// One block per (b, 2-row out tile). Per x-quarter (64 out cols): conv1 over
// 82 h1 cols -> conv2 over 80 px (5 MFMA tiles) -> conv3 over 64 cols.
// h1 layout: per-wave half-planes [wv=8][6 rows][82 cols][4ch] bf16 ->
// conv1 stores ONE contiguous ds_write_b128 per px-pair (conflict-free;
// round-5 layout was a 16-way conflict = 5.7M cycles).
// LDS: h1 31,488 + h2 23,040 (both union sf 51,200) + supd/sy2 16,640 + misc
// = 72,192 B -> 2 blocks/CU (16 waves).
#define H1COLS 82
#define H1PLANE (6*H1COLS*4)     // u16 per (q,hh) half-plane = 1968
#define H2COLS 80
#define H2PITCH 36               // u16 per px slot (32ch + 4 pad) = 18 dw
#define SM_H1    0               // 31,488 B  (union with sf 51,200 B)
#define SM_H2    31488           // 23,040 B
#define SM_SUPD  54528           // 8*260*4 = 8,320 B
#define SM_SY2   62848           // 8,320 B
#define SM_SCS   71168
#define SM_SSN   71368
#define SM_SWP   71568           // 576 B
#define SM_TOTAL 72192

__global__ __launch_bounds__(512, 4) void k_BC(const float* __restrict__ angles,
                                               const float* __restrict__ yprev,
                                               const float* __restrict__ yconc,
                                               const float* __restrict__ stepp,
                                               const float* __restrict__ w1,
                                               const float* __restrict__ b1,
                                               const float* __restrict__ b2,
                                               const float* __restrict__ w3,
                                               const float* __restrict__ b3,
                                               float* __restrict__ ws,
                                               float* __restrict__ dout) {
    __shared__ __align__(16) unsigned char smem[SM_TOTAL];
    float* sf   = (float*)(smem);                    // phase 1-2 only
    u16*   h1   = (u16*)(smem + SM_H1);              // phase 3+
    u16*   sh2  = (u16*)(smem + SM_H2);
    u32*   l32h2= (u32*)(smem + SM_H2);
    float (*supd)[260] = (float(*)[260])(smem + SM_SUPD);
    float (*sy2)[260]  = (float(*)[260])(smem + SM_SY2);
    float* scs = (float*)(smem + SM_SCS);
    float* ssn = (float*)(smem + SM_SSN);
    u32*   swp = (u32*)(smem + SM_SWP);

    int tid = threadIdx.x;
    int b = blockIdx.x >> 7, tile = blockIdx.x & 127;
    int y0 = tile << 1;

    // ---------------- phase 1: staging ----------------
    {   // sf: 51.2KB filtered sinogram for batch b
        const float4* s4 = (const float4*)(ws + OFF_FILT + b * (NANG * 256));
        float4* d4 = (float4*)sf;
        for (int idx = tid; idx < NANG * 64; idx += 512) d4[idx] = s4[idx];
    }
    if (tid < NANG) {
        float a_ = angles[tid];
        scs[tid] = cosf(a_); ssn[tid] = sinf(a_);
    }
    if (tid < 144) {   // w3 packed bf16 ch-pairs [t][kd]
        int t = tid >> 4, kd = tid & 15;
        swp[tid] = (u32)f2bf(w3[(2 * kd) * 9 + t]) | ((u32)f2bf(w3[(2 * kd + 1) * 9 + t]) << 16);
    }
    if (tid < 32) {    // supd halo cols (img -2,-1,256,257) = idx 0,1,258,259
        int r = tid >> 2, c4 = tid & 3;
        supd[r][(c4 < 2) ? c4 : (c4 + 256)] = 0.0f;
    }
    // sy2: y_concat rows y0-3..y0+4, col idx = img+2, zero-padded
    for (int idx = tid; idx < 8 * 260; idx += 512) {
        int r = idx / 260, c = idx - r * 260;
        int iy = y0 - 3 + r, ix = c - 2;
        sy2[r][c] = ((unsigned)iy < 256u && (unsigned)ix < 256u)
                        ? yconc[b * PIX + iy * 256 + ix] : 0.0f;
    }
    __syncthreads();

    // ---------------- phase 2: backproject 8 rows (y0-3..y0+4) ----------------
    {
        int j = tid & 255, r0 = tid >> 8;     // r0 in {0,1}; rows r0+2k, k=0..3
        float xx = (float)j - 127.5f;
        float yyb = (float)(y0 - 3 + r0) - 127.5f;
        float ac0 = 0.f, ac1 = 0.f, ac2 = 0.f, ac3 = 0.f;
        #pragma unroll 2
        for (int a = 0; a < NANG; ++a) {
            float cs = scs[a], sn = ssn[a];
            float d2 = sn + sn;
            float f0 = xx * cs + yyb * sn + 127.5f;
            float f1 = f0 + d2, f2 = f1 + d2, f3 = f2 + d2;
            #define BPSAMP(ff, accv) { \
                float fl = floorf(ff); int i0 = (int)fl; \
                i0 = min(max(i0, 0), 254); \
                float wq = ff - (float)i0; \
                float v = sf[a * 256 + i0] * (1.0f - wq) + sf[a * 256 + i0 + 1] * wq; \
                accv += (ff >= 0.0f && ff <= 255.0f) ? v : 0.0f; }
            BPSAMP(f0, ac0) BPSAMP(f1, ac1) BPSAMP(f2, ac2) BPSAMP(f3, ac3)
            #undef BPSAMP
        }
        float step = stepp[0];
        float accs[4] = {ac0, ac1, ac2, ac3};
        #pragma unroll
        for (int k = 0; k < 4; ++k) {
            int lr = r0 + 2 * k;
            int iy = y0 - 3 + lr;
            float val = 0.0f;
            if ((unsigned)iy < 256u) {
                float yy = (float)iy - 127.5f;
                float mk = (xx * xx + yy * yy <= 16384.0f) ? 1.0f : 0.0f;
                val = yprev[b * PIX + iy * 256 + j] + step * accs[k] * mk;
                if (iy >= y0 && iy <= y0 + 1)
                    dout[NPIX + b * PIX + iy * 256 + j] = val;   // second output
            }
            supd[lr][j + 2] = val;
        }
    }
    __syncthreads();   // supd done; sf dead (h1/h2 overwrite it)

    int wv = tid >> 6, lane = tid & 63;
    int m = lane & 15, quad = lane >> 4;
    float bias0 = b2[m], bias1 = b2[m + 16];
    const u16* __restrict__ w2bf = (const u16*)(ws + OFF_W2BF);

    // ---------------- phase 3: four x-quarters ----------------
    for (int xq = 0; xq < 4; ++xq) {
        int xbase = xq * 64;
        // ---- conv1: h1 cols L=0..81 <-> img px P = xbase-9+L, rows y0-2..y0+3
        {
            int oc0 = wv * 4;
            float W[72];
            const float4* wsrc = (const float4*)(w1 + oc0 * 18);
            #pragma unroll
            for (int i = 0; i < 18; ++i) ((float4*)W)[i] = wsrc[i];
            float bb0 = b1[oc0], bb1 = b1[oc0 + 1], bb2 = b1[oc0 + 2], bb3 = b1[oc0 + 3];
            u16* hp = h1 + wv * H1PLANE;
            #pragma unroll
            for (int it = 0; it < 4; ++it) {
                int idx = it * 64 + lane;            // 246 items: 6 rows x 41 pairs
                if (idx < 246) {
                    int lr = idx / 41, pp = idx - lr * 41;
                    int P = xbase - 9 + 2 * pp;      // odd; pair = (P, P+1)
                    int ir = y0 - 2 + lr;
                    int cgb = P + 1;                 // even; window idx cgb..cgb+3
                    cgb = min(max(cgb, 0), 256);     // clamp (out-of-range px zeroed)
                    float a00 = bb0, a01 = bb1, a02 = bb2, a03 = bb3;
                    float a10 = bb0, a11 = bb1, a12 = bb2, a13 = bb3;
                    #pragma unroll
                    for (int ky = 0; ky < 3; ++ky) {
                        float2 ua = *(const float2*)&supd[lr + ky][cgb];
                        float2 ub = *(const float2*)&supd[lr + ky][cgb + 2];
                        float2 ca = *(const float2*)&sy2[lr + ky][cgb];
                        float2 cb2 = *(const float2*)&sy2[lr + ky][cgb + 2];
                        float u[4]  = {ua.x, ua.y, ub.x, ub.y};
                        float c6[4] = {ca.x, ca.y, cb2.x, cb2.y};
                        #pragma unroll
                        for (int kx = 0; kx < 3; ++kx) {
                            int t = ky * 3 + kx;
                            float u0 = u[kx],     c0 = c6[kx];
                            float u1 = u[kx + 1], c1 = c6[kx + 1];
                            a00 += u0 * W[t]      + c0 * W[9 + t];
                            a01 += u0 * W[18 + t] + c0 * W[27 + t];
                            a02 += u0 * W[36 + t] + c0 * W[45 + t];
                            a03 += u0 * W[54 + t] + c0 * W[63 + t];
                            a10 += u1 * W[t]      + c1 * W[9 + t];
                            a11 += u1 * W[18 + t] + c1 * W[27 + t];
                            a12 += u1 * W[36 + t] + c1 * W[45 + t];
                            a13 += u1 * W[54 + t] + c1 * W[63 + t];
                        }
                    }
                    bool rowOK = (unsigned)ir < 256u;
                    bool v0 = rowOK && ((unsigned)P < 256u);
                    bool v1 = rowOK && ((unsigned)(P + 1) < 256u);
                    u32 q00 = 0, q01 = 0, q10 = 0, q11 = 0;
                    if (v0) {
                        q00 = (u32)f2bf(fmaxf(a00, 0.f)) | ((u32)f2bf(fmaxf(a01, 0.f)) << 16);
                        q01 = (u32)f2bf(fmaxf(a02, 0.f)) | ((u32)f2bf(fmaxf(a03, 0.f)) << 16);
                    }
                    if (v1) {
                        q10 = (u32)f2bf(fmaxf(a10, 0.f)) | ((u32)f2bf(fmaxf(a11, 0.f)) << 16);
                        q11 = (u32)f2bf(fmaxf(a12, 0.f)) | ((u32)f2bf(fmaxf(a13, 0.f)) << 16);
                    }
                    // one contiguous 16B store: px-pair x 4ch (conflict-free)
                    uint4* op = (uint4*)(hp + (lr * H1COLS + 2 * pp) * 4);
                    *op = make_uint4(q00, q01, q10, q11);
                }
            }
        }
        __syncthreads();

        // ---- conv2 MFMA: 20 tiles (4 h2 rows x 5 px-tiles of 16) over 8 waves
        {
            bfrag Bf[9][2];
            #pragma unroll
            for (int t = 0; t < 9; ++t) {
                const u16* wp = w2bf + t * 1024 + m * 32 + quad * 8;
                Bf[t][0] = *(const bfrag*)(wp);
                Bf[t][1] = *(const bfrag*)(wp + 16 * 32);
            }
            #pragma unroll
            for (int k = 0; k < 3; ++k) {
                int tl = wv + (k << 3);
                if (tl < 20) {
                    int ridx = tl / 5, pt = tl - ridx * 5;
                    int hy = y0 - 1 + ridx;
                    bool hyOK = (unsigned)hy < 256u;
                    int Lb = 16 * pt + m;
                    const u16* qp = h1 + quad * (2 * H1PLANE);
                    #define LDF(row, L, dst) { \
                        const u16* p0_ = qp + ((row) * H1COLS + (L)) * 4; \
                        uint2 lo_ = *(const uint2*)p0_; \
                        uint2 hi_ = *(const uint2*)(p0_ + H1PLANE); \
                        ((uint2*)&dst)[0] = lo_; ((uint2*)&dst)[1] = hi_; }
                    bfrag A0[3], A1[3];
                    #pragma unroll
                    for (int tx = 0; tx < 3; ++tx) LDF(ridx + 0, Lb + tx, A0[tx])
                    #pragma unroll
                    for (int tx = 0; tx < 3; ++tx) LDF(ridx + 1, Lb + tx, A1[tx])
                    ffrag c0 = {0.f, 0.f, 0.f, 0.f}, c1 = {0.f, 0.f, 0.f, 0.f};
                    #pragma unroll
                    for (int tx = 0; tx < 3; ++tx) {
                        c0 = __builtin_amdgcn_mfma_f32_16x16x32_bf16(A0[tx], Bf[tx][0], c0, 0, 0, 0);
                        c1 = __builtin_amdgcn_mfma_f32_16x16x32_bf16(A0[tx], Bf[tx][1], c1, 0, 0, 0);
                    }
                    #pragma unroll
                    for (int tx = 0; tx < 3; ++tx) LDF(ridx + 2, Lb + tx, A0[tx])
                    #pragma unroll
                    for (int tx = 0; tx < 3; ++tx) {
                        c0 = __builtin_amdgcn_mfma_f32_16x16x32_bf16(A1[tx], Bf[3 + tx][0], c0, 0, 0, 0);
                        c1 = __builtin_amdgcn_mfma_f32_16x16x32_bf16(A1[tx], Bf[3 + tx][1], c1, 0, 0, 0);
                    }
                    #pragma unroll
                    for (int tx = 0; tx < 3; ++tx) {
                        c0 = __builtin_amdgcn_mfma_f32_16x16x32_bf16(A0[tx], Bf[6 + tx][0], c0, 0, 0, 0);
                        c1 = __builtin_amdgcn_mfma_f32_16x16x32_bf16(A0[tx], Bf[6 + tx][1], c1, 0, 0, 0);
                    }
                    #undef LDF
                    #pragma unroll
                    for (int r = 0; r < 4; ++r) {
                        int pl = 16 * pt + quad * 4 + r;       // h2 local col
                        int pimg = xbase - 8 + pl;
                        bool ok = hyOK && ((unsigned)pimg < 256u);
                        float f0 = ok ? fmaxf(c0[r] + bias0, 0.0f) : 0.0f;
                        float f1 = ok ? fmaxf(c1[r] + bias1, 0.0f) : 0.0f;
                        u16* op = sh2 + (ridx * H2COLS + pl) * H2PITCH;
                        op[m]      = f2bf(f0);
                        op[m + 16] = f2bf(f1);
                    }
                }
            }
        }
        __syncthreads();

        // ---- conv3 (32->1): 128 out px, 4 lanes/px (8ch each), quad-reduce
        {
            int px_q = tid >> 2, g = tid & 3;
            int xl = px_q & 63, rr = px_q >> 6;
            int oy = y0 + rr;
            float acc = (g == 0) ? b3[0] : 0.0f;
            #pragma unroll
            for (int ky = 0; ky < 3; ++ky) {
                #pragma unroll
                for (int cx = 0; cx < 3; ++cx) {
                    int t = ky * 3 + cx;
                    int pl = xl + cx + 7;
                    const uint2* q2 = (const uint2*)(l32h2 + ((rr + ky) * H2COLS + pl) * 18 + g * 4);
                    const uint2* wp = (const uint2*)(swp + t * 16 + g * 4);
                    uint2 h0 = q2[0], h1v = q2[1];
                    uint2 w0 = wp[0], w1v = wp[1];
                    acc += __uint_as_float(h0.x << 16) * __uint_as_float(w0.x << 16)
                         + __uint_as_float(h0.x & 0xffff0000u) * __uint_as_float(w0.x & 0xffff0000u)
                         + __uint_as_float(h0.y << 16) * __uint_as_float(w0.y << 16)
                         + __uint_as_float(h0.y & 0xffff0000u) * __uint_as_float(w0.y & 0xffff0000u)
                         + __uint_as_float(h1v.x << 16) * __uint_as_float(w1v.x << 16)
                         + __uint_as_float(h1v.x & 0xffff0000u) * __uint_as_float(w1v.x & 0xffff0000u)
                         + __uint_as_float(h1v.y << 16) * __uint_as_float(w1v.y << 16)
                         + __uint_as_float(h1v.y & 0xffff0000u) * __uint_as_float(w1v.y & 0xffff0000u);
                }
            }
            acc += __shfl_xor(acc, 1, 64);
            acc += __shfl_xor(acc, 2, 64);
            if (g == 0)
                dout[b * PIX + oy * 256 + xbase + xl] = acc;   // first output
        }
        // no barrier: next conv1 writes h1 (all h1 readers barred already);
        // next conv2's h2 writes are behind the conv1 barrier.
    }
}

extern "C" void kernel_launch(void* const* d_in, const int* in_sizes, int n_in,
                              void* d_out, int out_size, void* d_ws, size_t ws_size,
                              hipStream_t stream) {
    const float* xsino  = (const float*)d_in[0];
    const float* yprev  = (const float*)d_in[1];
    const float* yconc  = (const float*)d_in[2];
    const float* angles = (const float*)d_in[3];
    const float* stepp  = (const float*)d_in[4];
    const float* w1 = (const float*)d_in[5];
    const float* b1 = (const float*)d_in[6];
    const float* w2 = (const float*)d_in[7];
    const float* b2 = (const float*)d_in[8];
    const float* w3 = (const float*)d_in[9];
    const float* b3 = (const float*)d_in[10];
    float* out = (float*)d_out;
    float* ws  = (float*)d_ws;

    k_A<<<209, 1024, 0, stream>>>(angles, yprev, xsino, w2, ws);
    k_BC<<<BATCH * 128, 512, 0, stream>>>(angles, yprev, yconc, stepp, w1, b1,
                                          b2, w3, b3, ws, out);
}

// Round 8
// 184.135 us; speedup vs baseline: 1.9366x; 1.9366x over previous
//
#include <hip/hip_runtime.h>
#include <math.h>

// Problem constants
#define IMGS 256
#define NANG 50
#define BATCH 4
#define NCNN 32
#define PIX (IMGS*IMGS)              // 65536
#define NPIX (BATCH*PIX)             // 262144

// Workspace layout (float offsets)
#define OFF_FILT  0          // 51200 filtered sinogram (b,a,s)
#define OFF_W2BF  51200      // 9216 bf16 = 4608 floats ([tap][oc][ic])

static constexpr double PI_D = 3.14159265358979323846;

typedef unsigned short u16;
typedef unsigned int   u32;
typedef unsigned long long u64;
typedef __bf16 bfrag __attribute__((ext_vector_type(8)));
typedef float  ffrag __attribute__((ext_vector_type(4)));

__device__ __forceinline__ u16 f2bf(float f) {
    u32 u = __float_as_uint(f);
    u += 0x7fffu + ((u >> 16) & 1u);     // RNE
    return (u16)(u >> 16);
}

// =========== K_A: radon forward + ramp filter (fused), + w2->bf16 ===========
// (unchanged, proven through rounds 0-6)
#define RPITCH_D 131            // dwords per LDS image row (odd => bank-friendly)
__global__ __launch_bounds__(1024, 4) void k_A(const float* __restrict__ angles,
                                               const float* __restrict__ yprev,
                                               const float* __restrict__ xsino,
                                               const float* __restrict__ w2,
                                               float* __restrict__ ws) {
    __shared__ u16 limg[258 * 262];      // 135,192 B
    __shared__ float spart[1024];
    __shared__ float staps[512];
    __shared__ float srow[256];
    int tid = threadIdx.x;
    int gid = blockIdx.x;
    if (gid >= 200) {                    // w2 conversion blocks
        int i = (gid - 200) * 1024 + tid;
        if (i < 9216) {
            int t = i >> 10, oc = (i >> 5) & 31, ic = i & 31;
            ((u16*)(ws + OFF_W2BF))[i] = f2bf(w2[(oc * 32 + ic) * 9 + t]);
        }
        return;
    }
    u32* l32 = (u32*)limg;
    int ra = gid;                        // b*50 + a
    int a = ra % NANG, b = ra / NANG;

    // ramp taps, closed form
    if (tid < 511) {
        int d = tid - 255;
        int n = d < 0 ? -d : d;
        double g;
        if (n == 0) {
            g = 0.5;
        } else {
            double th = PI_D * (double)n / 256.0;
            double S = (256.0 * cos(255.0 * th) - 255.0 * cos(256.0 * th) - 1.0)
                       / (2.0 * (1.0 - cos(th)));
            double sign = (n & 1) ? -1.0 : 1.0;
            g = (sign + S / 128.0) / 512.0;
        }
        staps[tid] = (float)(g * PI_D / 100.0);   // fold pi/(2A), A=50
    }

    // zero image borders
    for (int z = tid; z < 772; z += 1024) {
        int addr;
        if (z < 258)      addr = z * RPITCH_D;
        else if (z < 516) addr = (z - 258) * RPITCH_D + 129;
        else if (z < 644) addr = (z - 516) + 1;
        else              addr = 257 * RPITCH_D + (z - 644) + 1;
        l32[addr] = 0;
    }
    // stage interior: mask inline, fp32 -> bf16
    const float* __restrict__ src = yprev + b * PIX;
    for (int idx = tid; idx < 16384; idx += 1024) {
        int r = idx >> 6, c4 = (idx & 63) << 2;
        float4 v = *(const float4*)(src + r * 256 + c4);
        float di = (float)r - 127.5f;
        float rr = di * di;
        float d0 = (float)c4 - 127.5f;
        v.x = (rr + d0 * d0 <= 16384.0f) ? v.x : 0.0f;
        v.y = (rr + (d0 + 1.0f) * (d0 + 1.0f) <= 16384.0f) ? v.y : 0.0f;
        v.z = (rr + (d0 + 2.0f) * (d0 + 2.0f) <= 16384.0f) ? v.z : 0.0f;
        v.w = (rr + (d0 + 3.0f) * (d0 + 3.0f) <= 16384.0f) ? v.w : 0.0f;
        u32 p0 = (u32)f2bf(v.x) | ((u32)f2bf(v.y) << 16);
        u32 p1 = (u32)f2bf(v.z) | ((u32)f2bf(v.w) << 16);
        int dw = (r + 1) * RPITCH_D + (c4 >> 1) + 1;
        l32[dw] = p0; l32[dw + 1] = p1;
    }
    __syncthreads();

    float a_ = angles[a];
    float cs = cosf(a_), sn = sinf(a_);
    int lane = tid & 63, w = tid >> 6;   // 16 waves
    int s8 = lane & 7, t8 = lane >> 3;   // 8x8 patch coords
    int sA = w * 16 + s8;                // this thread's two s rows: sA, sA+8
    float scA = (float)sA - 127.5f;

    float loA = (float)(w * 16) - 127.5f, hiA = loA + 7.0f;
    float loB = loA + 8.0f,               hiB = hiA + 8.0f;
    float s2minA = fminf(loA * loA, hiA * hiA);
    float s2maxA = fmaxf(loA * loA, hiA * hiA);
    float s2minB = fminf(loB * loB, hiB * hiB);
    float s2maxB = fmaxf(loB * loB, hiB * hiB);
    float s2min  = fminf(s2minA, s2minB);
    float s2max  = fmaxf(s2maxA, s2maxB);
    float hmax = sqrtf(16770.25f - s2min);                 // 129.5^2
    int j_lo = max(0, (int)ceilf((120.5f - hmax) * 0.125f));
    int j_hi = min(31, (int)floorf((127.5f + hmax) * 0.125f));

    float tc0 = (float)t8 - 127.5f + 8.0f * (float)j_lo;
    float rowA = scA * sn + tc0 * cs + 127.5f;
    float colA = scA * cs - tc0 * sn + 127.5f;
    float rowB = rowA + 8.0f * sn;
    float colB = colA + 8.0f * cs;
    float cs8 = 8.0f * cs, sn8 = 8.0f * sn;
    float accA = 0.0f, accB = 0.0f;
    #pragma unroll 2
    for (int j = j_lo; j <= j_hi; ++j) {   // t = t8 + 8j
        float t0j = 8.0f * (float)j - 127.5f;
        float t7j = t0j + 7.0f;
        float tmax2 = fmaxf(t0j * t0j, t7j * t7j);
        if (s2max + tmax2 <= 16384.0f) {
            #pragma unroll
            for (int hh = 0; hh < 2; ++hh) {
                float rowv = hh ? rowB : rowA;
                float colv = hh ? colB : colA;
                float fr = floorf(rowv), fc = floorf(colv);
                float wr = rowv - fr, wc = colv - fc;
                int i0 = (int)fr, j0 = (int)fc;
                int ca = j0 + 2;
                int ka = ca >> 1;
                int sh = (ca & 1) << 4;
                int dw = (i0 + 1) * RPITCH_D + ka;
                u32 A = l32[dw],            C = l32[dw + 1];
                u32 B = l32[dw + RPITCH_D], D = l32[dw + RPITCH_D + 1];
                u32 top = (u32)((((u64)C << 32) | (u64)A) >> sh);
                u32 bot = (u32)((((u64)D << 32) | (u64)B) >> sh);
                float tl = __uint_as_float(top << 16);
                float tr_ = __uint_as_float(top & 0xffff0000u);
                float bl = __uint_as_float(bot << 16);
                float br = __uint_as_float(bot & 0xffff0000u);
                float tv = tl + (tr_ - tl) * wc;
                float bv = bl + (br - bl) * wc;
                float sv = tv + (bv - tv) * wr;
                if (hh) accB += sv; else accA += sv;
            }
        } else {
            #pragma unroll
            for (int hh = 0; hh < 2; ++hh) {
                float rowv = hh ? rowB : rowA;
                float colv = hh ? colB : colA;
                float fr = floorf(rowv), fc = floorf(colv);
                float wr = rowv - fr, wc = colv - fc;
                int i0 = (int)fr, j0 = (int)fc;
                bool valid = (rowv > -1.0f) & (rowv < 256.0f) & (colv > -1.0f) & (colv < 256.0f);
                int i0c = min(max(i0, -1), 255);
                int j0c = min(max(j0, -1), 255);
                int ca = j0c + 2;
                int ka = ca >> 1;
                int sh = (ca & 1) << 4;
                int dw = (i0c + 1) * RPITCH_D + ka;
                u32 A = l32[dw],            C = l32[dw + 1];
                u32 B = l32[dw + RPITCH_D], D = l32[dw + RPITCH_D + 1];
                u32 top = (u32)((((u64)C << 32) | (u64)A) >> sh);
                u32 bot = (u32)((((u64)D << 32) | (u64)B) >> sh);
                float tl = __uint_as_float(top << 16);
                float tr_ = __uint_as_float(top & 0xffff0000u);
                float bl = __uint_as_float(bot << 16);
                float br = __uint_as_float(bot & 0xffff0000u);
                float tv = tl + (tr_ - tl) * wc;
                float bv = bl + (br - bl) * wc;
                float sv = tv + (bv - tv) * wr;
                sv = valid ? sv : 0.0f;
                if (hh) accB += sv; else accA += sv;
            }
        }
        rowA += cs8; colA -= sn8; rowB += cs8; colB -= sn8;
    }
    accA += __shfl_xor(accA, 8, 64);
    accA += __shfl_xor(accA, 16, 64);
    accA += __shfl_xor(accA, 32, 64);
    accB += __shfl_xor(accB, 8, 64);
    accB += __shfl_xor(accB, 16, 64);
    accB += __shfl_xor(accB, 32, 64);
    if (t8 == 0) { spart[sA] = accA; spart[sA + 8] = accB; }
    __syncthreads();
    if (tid < 256)
        srow[tid] = spart[tid] - xsino[ra * 256 + tid];
    __syncthreads();
    {   // 511-tap filter, split 4 ways over taps
        int s = tid & 255, q = tid >> 8;
        float fa = 0.0f;
        int m0 = q * 64;
        #pragma unroll 8
        for (int m = m0; m < m0 + 64; ++m) fa += srow[m] * staps[s - m + 255];
        spart[tid] = fa;
    }
    __syncthreads();
    if (tid < 256)
        ws[OFF_FILT + ra * 256 + tid] =
            spart[tid] + spart[tid + 256] + spart[tid + 512] + spart[tid + 768];
}

// =========== K_BC v3: fused, x-quartered; LAUNCH BOUNDS FIXED ============
// Round-6 structure (correct, passed) with __launch_bounds__(512, 2):
// the 2nd arg is min BLOCKS/CU on this toolchain (observed: (512,2)->120
// VGPR, (512,4)->64 VGPR + 800MB scratch spill). (512,2) => 128-VGPR cap,
// natural demand ~120, LDS 72.2KB <= 80KB => 2 blocks/CU, no spill.
// #pragma unroll 1 on the xq loop keeps W (conv1) and Bf (conv2) live
// ranges disjoint so the compiler can't hoist both past 128.
#define H1COLS 82
#define H1PLANE (6*H1COLS*4)     // u16 per (q,hh) half-plane = 1968
#define H2COLS 80
#define H2PITCH 36               // u16 per px slot (32ch + 4 pad) = 18 dw
#define SM_H1    0               // 31,488 B  (union with sf 51,200 B)
#define SM_H2    31488           // 23,040 B
#define SM_SUPD  54528           // 8*260*4 = 8,320 B
#define SM_SY2   62848           // 8,320 B
#define SM_SCS   71168
#define SM_SSN   71368
#define SM_SWP   71568           // 576 B
#define SM_TOTAL 72192

__global__ __launch_bounds__(512, 2) void k_BC(const float* __restrict__ angles,
                                               const float* __restrict__ yprev,
                                               const float* __restrict__ yconc,
                                               const float* __restrict__ stepp,
                                               const float* __restrict__ w1,
                                               const float* __restrict__ b1,
                                               const float* __restrict__ b2,
                                               const float* __restrict__ w3,
                                               const float* __restrict__ b3,
                                               float* __restrict__ ws,
                                               float* __restrict__ dout) {
    __shared__ __align__(16) unsigned char smem[SM_TOTAL];
    float* sf   = (float*)(smem);                    // phase 1-2 only
    u16*   h1   = (u16*)(smem + SM_H1);              // phase 3+
    u16*   sh2  = (u16*)(smem + SM_H2);
    u32*   l32h2= (u32*)(smem + SM_H2);
    float (*supd)[260] = (float(*)[260])(smem + SM_SUPD);
    float (*sy2)[260]  = (float(*)[260])(smem + SM_SY2);
    float* scs = (float*)(smem + SM_SCS);
    float* ssn = (float*)(smem + SM_SSN);
    u32*   swp = (u32*)(smem + SM_SWP);

    int tid = threadIdx.x;
    int b = blockIdx.x >> 7, tile = blockIdx.x & 127;
    int y0 = tile << 1;

    // ---------------- phase 1: staging ----------------
    {   // sf: 51.2KB filtered sinogram for batch b
        const float4* s4 = (const float4*)(ws + OFF_FILT + b * (NANG * 256));
        float4* d4 = (float4*)sf;
        for (int idx = tid; idx < NANG * 64; idx += 512) d4[idx] = s4[idx];
    }
    if (tid < NANG) {
        float a_ = angles[tid];
        scs[tid] = cosf(a_); ssn[tid] = sinf(a_);
    }
    if (tid < 144) {   // w3 packed bf16 ch-pairs [t][kd]
        int t = tid >> 4, kd = tid & 15;
        swp[tid] = (u32)f2bf(w3[(2 * kd) * 9 + t]) | ((u32)f2bf(w3[(2 * kd + 1) * 9 + t]) << 16);
    }
    if (tid < 32) {    // supd halo cols (img -2,-1,256,257) = idx 0,1,258,259
        int r = tid >> 2, c4 = tid & 3;
        supd[r][(c4 < 2) ? c4 : (c4 + 256)] = 0.0f;
    }
    // sy2: y_concat rows y0-3..y0+4, col idx = img+2, zero-padded
    for (int idx = tid; idx < 8 * 260; idx += 512) {
        int r = idx / 260, c = idx - r * 260;
        int iy = y0 - 3 + r, ix = c - 2;
        sy2[r][c] = ((unsigned)iy < 256u && (unsigned)ix < 256u)
                        ? yconc[b * PIX + iy * 256 + ix] : 0.0f;
    }
    __syncthreads();

    // ---------------- phase 2: backproject 8 rows (y0-3..y0+4) ----------------
    {
        int j = tid & 255, r0 = tid >> 8;     // r0 in {0,1}; rows r0+2k, k=0..3
        float xx = (float)j - 127.5f;
        float yyb = (float)(y0 - 3 + r0) - 127.5f;
        float ac0 = 0.f, ac1 = 0.f, ac2 = 0.f, ac3 = 0.f;
        #pragma unroll 2
        for (int a = 0; a < NANG; ++a) {
            float cs = scs[a], sn = ssn[a];
            float d2 = sn + sn;
            float f0 = xx * cs + yyb * sn + 127.5f;
            float f1 = f0 + d2, f2 = f1 + d2, f3 = f2 + d2;
            #define BPSAMP(ff, accv) { \
                float fl = floorf(ff); int i0 = (int)fl; \
                i0 = min(max(i0, 0), 254); \
                float wq = ff - (float)i0; \
                float v = sf[a * 256 + i0] * (1.0f - wq) + sf[a * 256 + i0 + 1] * wq; \
                accv += (ff >= 0.0f && ff <= 255.0f) ? v : 0.0f; }
            BPSAMP(f0, ac0) BPSAMP(f1, ac1) BPSAMP(f2, ac2) BPSAMP(f3, ac3)
            #undef BPSAMP
        }
        float step = stepp[0];
        float accs[4] = {ac0, ac1, ac2, ac3};
        #pragma unroll
        for (int k = 0; k < 4; ++k) {
            int lr = r0 + 2 * k;
            int iy = y0 - 3 + lr;
            float val = 0.0f;
            if ((unsigned)iy < 256u) {
                float yy = (float)iy - 127.5f;
                float mk = (xx * xx + yy * yy <= 16384.0f) ? 1.0f : 0.0f;
                val = yprev[b * PIX + iy * 256 + j] + step * accs[k] * mk;
                if (iy >= y0 && iy <= y0 + 1)
                    dout[NPIX + b * PIX + iy * 256 + j] = val;   // second output
            }
            supd[lr][j + 2] = val;
        }
    }
    __syncthreads();   // supd done; sf dead (h1/h2 overwrite it)

    int wv = tid >> 6, lane = tid & 63;
    int m = lane & 15, quad = lane >> 4;
    float bias0 = b2[m], bias1 = b2[m + 16];
    const u16* __restrict__ w2bf = (const u16*)(ws + OFF_W2BF);

    // ---------------- phase 3: four x-quarters ----------------
    #pragma unroll 1
    for (int xq = 0; xq < 4; ++xq) {
        int xbase = xq * 64;
        // ---- conv1: h1 cols L=0..81 <-> img px P = xbase-9+L, rows y0-2..y0+3
        {
            int oc0 = wv * 4;
            float W[72];
            const float4* wsrc = (const float4*)(w1 + oc0 * 18);
            #pragma unroll
            for (int i = 0; i < 18; ++i) ((float4*)W)[i] = wsrc[i];
            float bb0 = b1[oc0], bb1 = b1[oc0 + 1], bb2 = b1[oc0 + 2], bb3 = b1[oc0 + 3];
            u16* hp = h1 + wv * H1PLANE;
            #pragma unroll
            for (int it = 0; it < 4; ++it) {
                int idx = it * 64 + lane;            // 246 items: 6 rows x 41 pairs
                if (idx < 246) {
                    int lr = idx / 41, pp = idx - lr * 41;
                    int P = xbase - 9 + 2 * pp;      // odd; pair = (P, P+1)
                    int ir = y0 - 2 + lr;
                    int cgb = P + 1;                 // even; window idx cgb..cgb+3
                    cgb = min(max(cgb, 0), 256);     // clamp (out-of-range px zeroed)
                    float a00 = bb0, a01 = bb1, a02 = bb2, a03 = bb3;
                    float a10 = bb0, a11 = bb1, a12 = bb2, a13 = bb3;
                    #pragma unroll
                    for (int ky = 0; ky < 3; ++ky) {
                        float2 ua = *(const float2*)&supd[lr + ky][cgb];
                        float2 ub = *(const float2*)&supd[lr + ky][cgb + 2];
                        float2 ca = *(const float2*)&sy2[lr + ky][cgb];
                        float2 cb2 = *(const float2*)&sy2[lr + ky][cgb + 2];
                        float u[4]  = {ua.x, ua.y, ub.x, ub.y};
                        float c6[4] = {ca.x, ca.y, cb2.x, cb2.y};
                        #pragma unroll
                        for (int kx = 0; kx < 3; ++kx) {
                            int t = ky * 3 + kx;
                            float u0 = u[kx],     c0 = c6[kx];
                            float u1 = u[kx + 1], c1 = c6[kx + 1];
                            a00 += u0 * W[t]      + c0 * W[9 + t];
                            a01 += u0 * W[18 + t] + c0 * W[27 + t];
                            a02 += u0 * W[36 + t] + c0 * W[45 + t];
                            a03 += u0 * W[54 + t] + c0 * W[63 + t];
                            a10 += u1 * W[t]      + c1 * W[9 + t];
                            a11 += u1 * W[18 + t] + c1 * W[27 + t];
                            a12 += u1 * W[36 + t] + c1 * W[45 + t];
                            a13 += u1 * W[54 + t] + c1 * W[63 + t];
                        }
                    }
                    bool rowOK = (unsigned)ir < 256u;
                    bool v0 = rowOK && ((unsigned)P < 256u);
                    bool v1 = rowOK && ((unsigned)(P + 1) < 256u);
                    u32 q00 = 0, q01 = 0, q10 = 0, q11 = 0;
                    if (v0) {
                        q00 = (u32)f2bf(fmaxf(a00, 0.f)) | ((u32)f2bf(fmaxf(a01, 0.f)) << 16);
                        q01 = (u32)f2bf(fmaxf(a02, 0.f)) | ((u32)f2bf(fmaxf(a03, 0.f)) << 16);
                    }
                    if (v1) {
                        q10 = (u32)f2bf(fmaxf(a10, 0.f)) | ((u32)f2bf(fmaxf(a11, 0.f)) << 16);
                        q11 = (u32)f2bf(fmaxf(a12, 0.f)) | ((u32)f2bf(fmaxf(a13, 0.f)) << 16);
                    }
                    // one contiguous 16B store: px-pair x 4ch (conflict-free)
                    uint4* op = (uint4*)(hp + (lr * H1COLS + 2 * pp) * 4);
                    *op = make_uint4(q00, q01, q10, q11);
                }
            }
        }
        __syncthreads();

        // ---- conv2 MFMA: 20 tiles (4 h2 rows x 5 px-tiles of 16) over 8 waves
        {
            bfrag Bf[9][2];
            #pragma unroll
            for (int t = 0; t < 9; ++t) {
                const u16* wp = w2bf + t * 1024 + m * 32 + quad * 8;
                Bf[t][0] = *(const bfrag*)(wp);
                Bf[t][1] = *(const bfrag*)(wp + 16 * 32);
            }
            #pragma unroll
            for (int k = 0; k < 3; ++k) {
                int tl = wv + (k << 3);
                if (tl < 20) {
                    int ridx = tl / 5, pt = tl - ridx * 5;
                    int hy = y0 - 1 + ridx;
                    bool hyOK = (unsigned)hy < 256u;
                    int Lb = 16 * pt + m;
                    const u16* qp = h1 + quad * (2 * H1PLANE);
                    #define LDF(row, L, dst) { \
                        const u16* p0_ = qp + ((row) * H1COLS + (L)) * 4; \
                        uint2 lo_ = *(const uint2*)p0_; \
                        uint2 hi_ = *(const uint2*)(p0_ + H1PLANE); \
                        ((uint2*)&dst)[0] = lo_; ((uint2*)&dst)[1] = hi_; }
                    bfrag A0[3], A1[3];
                    #pragma unroll
                    for (int tx = 0; tx < 3; ++tx) LDF(ridx + 0, Lb + tx, A0[tx])
                    #pragma unroll
                    for (int tx = 0; tx < 3; ++tx) LDF(ridx + 1, Lb + tx, A1[tx])
                    ffrag c0 = {0.f, 0.f, 0.f, 0.f}, c1 = {0.f, 0.f, 0.f, 0.f};
                    #pragma unroll
                    for (int tx = 0; tx < 3; ++tx) {
                        c0 = __builtin_amdgcn_mfma_f32_16x16x32_bf16(A0[tx], Bf[tx][0], c0, 0, 0, 0);
                        c1 = __builtin_amdgcn_mfma_f32_16x16x32_bf16(A0[tx], Bf[tx][1], c1, 0, 0, 0);
                    }
                    #pragma unroll
                    for (int tx = 0; tx < 3; ++tx) LDF(ridx + 2, Lb + tx, A0[tx])
                    #pragma unroll
                    for (int tx = 0; tx < 3; ++tx) {
                        c0 = __builtin_amdgcn_mfma_f32_16x16x32_bf16(A1[tx], Bf[3 + tx][0], c0, 0, 0, 0);
                        c1 = __builtin_amdgcn_mfma_f32_16x16x32_bf16(A1[tx], Bf[3 + tx][1], c1, 0, 0, 0);
                    }
                    #pragma unroll
                    for (int tx = 0; tx < 3; ++tx) {
                        c0 = __builtin_amdgcn_mfma_f32_16x16x32_bf16(A0[tx], Bf[6 + tx][0], c0, 0, 0, 0);
                        c1 = __builtin_amdgcn_mfma_f32_16x16x32_bf16(A0[tx], Bf[6 + tx][1], c1, 0, 0, 0);
                    }
                    #undef LDF
                    #pragma unroll
                    for (int r = 0; r < 4; ++r) {
                        int pl = 16 * pt + quad * 4 + r;       // h2 local col
                        int pimg = xbase - 8 + pl;
                        bool ok = hyOK && ((unsigned)pimg < 256u);
                        float f0 = ok ? fmaxf(c0[r] + bias0, 0.0f) : 0.0f;
                        float f1 = ok ? fmaxf(c1[r] + bias1, 0.0f) : 0.0f;
                        u16* op = sh2 + (ridx * H2COLS + pl) * H2PITCH;
                        op[m]      = f2bf(f0);
                        op[m + 16] = f2bf(f1);
                    }
                }
            }
        }
        __syncthreads();

        // ---- conv3 (32->1): 128 out px, 4 lanes/px (8ch each), quad-reduce
        {
            int px_q = tid >> 2, g = tid & 3;
            int xl = px_q & 63, rr = px_q >> 6;
            int oy = y0 + rr;
            float acc = (g == 0) ? b3[0] : 0.0f;
            #pragma unroll
            for (int ky = 0; ky < 3; ++ky) {
                #pragma unroll
                for (int cx = 0; cx < 3; ++cx) {
                    int t = ky * 3 + cx;
                    int pl = xl + cx + 7;
                    const uint2* q2 = (const uint2*)(l32h2 + ((rr + ky) * H2COLS + pl) * 18 + g * 4);
                    const uint2* wp = (const uint2*)(swp + t * 16 + g * 4);
                    uint2 h0 = q2[0], h1v = q2[1];
                    uint2 w0 = wp[0], w1v = wp[1];
                    acc += __uint_as_float(h0.x << 16) * __uint_as_float(w0.x << 16)
                         + __uint_as_float(h0.x & 0xffff0000u) * __uint_as_float(w0.x & 0xffff0000u)
                         + __uint_as_float(h0.y << 16) * __uint_as_float(w0.y << 16)
                         + __uint_as_float(h0.y & 0xffff0000u) * __uint_as_float(w0.y & 0xffff0000u)
                         + __uint_as_float(h1v.x << 16) * __uint_as_float(w1v.x << 16)
                         + __uint_as_float(h1v.x & 0xffff0000u) * __uint_as_float(w1v.x & 0xffff0000u)
                         + __uint_as_float(h1v.y << 16) * __uint_as_float(w1v.y << 16)
                         + __uint_as_float(h1v.y & 0xffff0000u) * __uint_as_float(w1v.y & 0xffff0000u);
                }
            }
            acc += __shfl_xor(acc, 1, 64);
            acc += __shfl_xor(acc, 2, 64);
            if (g == 0)
                dout[b * PIX + oy * 256 + xbase + xl] = acc;   // first output
        }
        // no barrier: next conv1 writes h1 (all h1 readers barred already);
        // next conv2's h2 writes are behind the conv1 barrier.
    }
}

extern "C" void kernel_launch(void* const* d_in, const int* in_sizes, int n_in,
                              void* d_out, int out_size, void* d_ws, size_t ws_size,
                              hipStream_t stream) {
    const float* xsino  = (const float*)d_in[0];
    const float* yprev  = (const float*)d_in[1];
    const float* yconc  = (const float*)d_in[2];
    const float* angles = (const float*)d_in[3];
    const float* stepp  = (const float*)d_in[4];
    const float* w1 = (const float*)d_in[5];
    const float* b1 = (const float*)d_in[6];
    const float* w2 = (const float*)d_in[7];
    const float* b2 = (const float*)d_in[8];
    const float* w3 = (const float*)d_in[9];
    const float* b3 = (const float*)d_in[10];
    float* out = (float*)d_out;
    float* ws  = (float*)d_ws;

    k_A<<<209, 1024, 0, stream>>>(angles, yprev, xsino, w2, ws);
    k_BC<<<BATCH * 128, 512, 0, stream>>>(angles, yprev, yconc, stepp, w1, b1,
                                          b2, w3, b3, ws, out);
}

// Round 9
// 169.514 us; speedup vs baseline: 2.1037x; 1.0863x over previous
//
#include <hip/hip_runtime.h>
#include <math.h>

// Problem constants
#define IMGS 256
#define NANG 50
#define BATCH 4
#define NCNN 32
#define PIX (IMGS*IMGS)              // 65536
#define NPIX (BATCH*PIX)             // 262144

// Workspace layout (float offsets)
#define OFF_FILT  0          // 51200 filtered sinogram (b,a,s)
#define OFF_W2BF  51200      // 9216 bf16 = 4608 floats ([tap][oc][ic])

static constexpr double PI_D = 3.14159265358979323846;

typedef unsigned short u16;
typedef unsigned int   u32;
typedef unsigned long long u64;
typedef __bf16 bfrag __attribute__((ext_vector_type(8)));
typedef float  ffrag __attribute__((ext_vector_type(4)));

__device__ __forceinline__ u16 f2bf(float f) {
    u32 u = __float_as_uint(f);
    u += 0x7fffu + ((u >> 16) & 1u);     // RNE
    return (u16)(u >> 16);
}

// =========== K_A: radon forward + ramp filter (fused), + w2->bf16 ===========
// (unchanged, proven through rounds 0-8)
#define RPITCH_D 131            // dwords per LDS image row (odd => bank-friendly)
__global__ __launch_bounds__(1024, 4) void k_A(const float* __restrict__ angles,
                                               const float* __restrict__ yprev,
                                               const float* __restrict__ xsino,
                                               const float* __restrict__ w2,
                                               float* __restrict__ ws) {
    __shared__ u16 limg[258 * 262];      // 135,192 B
    __shared__ float spart[1024];
    __shared__ float staps[512];
    __shared__ float srow[256];
    int tid = threadIdx.x;
    int gid = blockIdx.x;
    if (gid >= 200) {                    // w2 conversion blocks
        int i = (gid - 200) * 1024 + tid;
        if (i < 9216) {
            int t = i >> 10, oc = (i >> 5) & 31, ic = i & 31;
            ((u16*)(ws + OFF_W2BF))[i] = f2bf(w2[(oc * 32 + ic) * 9 + t]);
        }
        return;
    }
    u32* l32 = (u32*)limg;
    int ra = gid;                        // b*50 + a
    int a = ra % NANG, b = ra / NANG;

    // ramp taps, closed form
    if (tid < 511) {
        int d = tid - 255;
        int n = d < 0 ? -d : d;
        double g;
        if (n == 0) {
            g = 0.5;
        } else {
            double th = PI_D * (double)n / 256.0;
            double S = (256.0 * cos(255.0 * th) - 255.0 * cos(256.0 * th) - 1.0)
                       / (2.0 * (1.0 - cos(th)));
            double sign = (n & 1) ? -1.0 : 1.0;
            g = (sign + S / 128.0) / 512.0;
        }
        staps[tid] = (float)(g * PI_D / 100.0);   // fold pi/(2A), A=50
    }

    // zero image borders
    for (int z = tid; z < 772; z += 1024) {
        int addr;
        if (z < 258)      addr = z * RPITCH_D;
        else if (z < 516) addr = (z - 258) * RPITCH_D + 129;
        else if (z < 644) addr = (z - 516) + 1;
        else              addr = 257 * RPITCH_D + (z - 644) + 1;
        l32[addr] = 0;
    }
    // stage interior: mask inline, fp32 -> bf16
    const float* __restrict__ src = yprev + b * PIX;
    for (int idx = tid; idx < 16384; idx += 1024) {
        int r = idx >> 6, c4 = (idx & 63) << 2;
        float4 v = *(const float4*)(src + r * 256 + c4);
        float di = (float)r - 127.5f;
        float rr = di * di;
        float d0 = (float)c4 - 127.5f;
        v.x = (rr + d0 * d0 <= 16384.0f) ? v.x : 0.0f;
        v.y = (rr + (d0 + 1.0f) * (d0 + 1.0f) <= 16384.0f) ? v.y : 0.0f;
        v.z = (rr + (d0 + 2.0f) * (d0 + 2.0f) <= 16384.0f) ? v.z : 0.0f;
        v.w = (rr + (d0 + 3.0f) * (d0 + 3.0f) <= 16384.0f) ? v.w : 0.0f;
        u32 p0 = (u32)f2bf(v.x) | ((u32)f2bf(v.y) << 16);
        u32 p1 = (u32)f2bf(v.z) | ((u32)f2bf(v.w) << 16);
        int dw = (r + 1) * RPITCH_D + (c4 >> 1) + 1;
        l32[dw] = p0; l32[dw + 1] = p1;
    }
    __syncthreads();

    float a_ = angles[a];
    float cs = cosf(a_), sn = sinf(a_);
    int lane = tid & 63, w = tid >> 6;   // 16 waves
    int s8 = lane & 7, t8 = lane >> 3;   // 8x8 patch coords
    int sA = w * 16 + s8;                // this thread's two s rows: sA, sA+8
    float scA = (float)sA - 127.5f;

    float loA = (float)(w * 16) - 127.5f, hiA = loA + 7.0f;
    float loB = loA + 8.0f,               hiB = hiA + 8.0f;
    float s2minA = fminf(loA * loA, hiA * hiA);
    float s2maxA = fmaxf(loA * loA, hiA * hiA);
    float s2minB = fminf(loB * loB, hiB * hiB);
    float s2maxB = fmaxf(loB * loB, hiB * hiB);
    float s2min  = fminf(s2minA, s2minB);
    float s2max  = fmaxf(s2maxA, s2maxB);
    float hmax = sqrtf(16770.25f - s2min);                 // 129.5^2
    int j_lo = max(0, (int)ceilf((120.5f - hmax) * 0.125f));
    int j_hi = min(31, (int)floorf((127.5f + hmax) * 0.125f));

    float tc0 = (float)t8 - 127.5f + 8.0f * (float)j_lo;
    float rowA = scA * sn + tc0 * cs + 127.5f;
    float colA = scA * cs - tc0 * sn + 127.5f;
    float rowB = rowA + 8.0f * sn;
    float colB = colA + 8.0f * cs;
    float cs8 = 8.0f * cs, sn8 = 8.0f * sn;
    float accA = 0.0f, accB = 0.0f;
    #pragma unroll 2
    for (int j = j_lo; j <= j_hi; ++j) {   // t = t8 + 8j
        float t0j = 8.0f * (float)j - 127.5f;
        float t7j = t0j + 7.0f;
        float tmax2 = fmaxf(t0j * t0j, t7j * t7j);
        if (s2max + tmax2 <= 16384.0f) {
            #pragma unroll
            for (int hh = 0; hh < 2; ++hh) {
                float rowv = hh ? rowB : rowA;
                float colv = hh ? colB : colA;
                float fr = floorf(rowv), fc = floorf(colv);
                float wr = rowv - fr, wc = colv - fc;
                int i0 = (int)fr, j0 = (int)fc;
                int ca = j0 + 2;
                int ka = ca >> 1;
                int sh = (ca & 1) << 4;
                int dw = (i0 + 1) * RPITCH_D + ka;
                u32 A = l32[dw],            C = l32[dw + 1];
                u32 B = l32[dw + RPITCH_D], D = l32[dw + RPITCH_D + 1];
                u32 top = (u32)((((u64)C << 32) | (u64)A) >> sh);
                u32 bot = (u32)((((u64)D << 32) | (u64)B) >> sh);
                float tl = __uint_as_float(top << 16);
                float tr_ = __uint_as_float(top & 0xffff0000u);
                float bl = __uint_as_float(bot << 16);
                float br = __uint_as_float(bot & 0xffff0000u);
                float tv = tl + (tr_ - tl) * wc;
                float bv = bl + (br - bl) * wc;
                float sv = tv + (bv - tv) * wr;
                if (hh) accB += sv; else accA += sv;
            }
        } else {
            #pragma unroll
            for (int hh = 0; hh < 2; ++hh) {
                float rowv = hh ? rowB : rowA;
                float colv = hh ? colB : colA;
                float fr = floorf(rowv), fc = floorf(colv);
                float wr = rowv - fr, wc = colv - fc;
                int i0 = (int)fr, j0 = (int)fc;
                bool valid = (rowv > -1.0f) & (rowv < 256.0f) & (colv > -1.0f) & (colv < 256.0f);
                int i0c = min(max(i0, -1), 255);
                int j0c = min(max(j0, -1), 255);
                int ca = j0c + 2;
                int ka = ca >> 1;
                int sh = (ca & 1) << 4;
                int dw = (i0c + 1) * RPITCH_D + ka;
                u32 A = l32[dw],            C = l32[dw + 1];
                u32 B = l32[dw + RPITCH_D], D = l32[dw + RPITCH_D + 1];
                u32 top = (u32)((((u64)C << 32) | (u64)A) >> sh);
                u32 bot = (u32)((((u64)D << 32) | (u64)B) >> sh);
                float tl = __uint_as_float(top << 16);
                float tr_ = __uint_as_float(top & 0xffff0000u);
                float bl = __uint_as_float(bot << 16);
                float br = __uint_as_float(bot & 0xffff0000u);
                float tv = tl + (tr_ - tl) * wc;
                float bv = bl + (br - bl) * wc;
                float sv = tv + (bv - tv) * wr;
                sv = valid ? sv : 0.0f;
                if (hh) accB += sv; else accA += sv;
            }
        }
        rowA += cs8; colA -= sn8; rowB += cs8; colB -= sn8;
    }
    accA += __shfl_xor(accA, 8, 64);
    accA += __shfl_xor(accA, 16, 64);
    accA += __shfl_xor(accA, 32, 64);
    accB += __shfl_xor(accB, 8, 64);
    accB += __shfl_xor(accB, 16, 64);
    accB += __shfl_xor(accB, 32, 64);
    if (t8 == 0) { spart[sA] = accA; spart[sA + 8] = accB; }
    __syncthreads();
    if (tid < 256)
        srow[tid] = spart[tid] - xsino[ra * 256 + tid];
    __syncthreads();
    {   // 511-tap filter, split 4 ways over taps
        int s = tid & 255, q = tid >> 8;
        float fa = 0.0f;
        int m0 = q * 64;
        #pragma unroll 8
        for (int m = m0; m < m0 + 64; ++m) fa += srow[m] * staps[s - m + 255];
        spart[tid] = fa;
    }
    __syncthreads();
    if (tid < 256)
        ws[OFF_FILT + ra * 256 + tid] =
            spart[tid] + spart[tid + 256] + spart[tid + 512] + spart[tid + 768];
}

// =========== K_BC v4: fused, R=4 out-rows/block, conv3 reverted ==========
// 256 blocks (1/CU, no tail) x 512 thr. Per block: backproj 10 rows ->
// conv1 8 rows -> (4 x-quarters) conv2 6 rows x 80 px -> conv3 4x64 px.
// Halo recompute per out-row drops 25-37% vs R=2. conv3 = one px/thread
// (stride-1 slots -> 2-way banks = free; the 4-lane/px variant was a
// systematic 4-way conflict = 6.4M cycles).
// LDS 98.3 KB -> 1 block/CU; launch_bounds(512,1) -> 256-VGPR cap (no spill).
#define H1ROWS 8
#define H1COLS 82
#define H1PLANE (H1ROWS*H1COLS*4)    // u16 per (q,hh) half-plane = 2624
#define H2ROWS 6
#define H2COLS 80
#define H2PITCH 36                   // u16 per px slot (32ch + 4 pad) = 18 dw
#define SM_H1    0                   // 8*2624*2 = 41,984 B (union sf 51,200)
#define SM_H2    41984               // 6*80*36*2 = 34,560 B
#define SM_SUPD  76544               // 10*260*4 = 10,400 B
#define SM_SY2   86944               // 10,400 B
#define SM_SCS   97344
#define SM_SSN   97544
#define SM_SWP   97744               // 576 B
#define SM_TOTAL 98320

__global__ __launch_bounds__(512, 1) void k_BC(const float* __restrict__ angles,
                                               const float* __restrict__ yprev,
                                               const float* __restrict__ yconc,
                                               const float* __restrict__ stepp,
                                               const float* __restrict__ w1,
                                               const float* __restrict__ b1,
                                               const float* __restrict__ b2,
                                               const float* __restrict__ w3,
                                               const float* __restrict__ b3,
                                               float* __restrict__ ws,
                                               float* __restrict__ dout) {
    __shared__ __align__(16) unsigned char smem[SM_TOTAL];
    float* sf   = (float*)(smem);                    // phase 1-2 only
    u16*   h1   = (u16*)(smem + SM_H1);              // phase 3+
    u16*   sh2  = (u16*)(smem + SM_H2);
    u32*   l32h2= (u32*)(smem + SM_H2);
    float (*supd)[260] = (float(*)[260])(smem + SM_SUPD);
    float (*sy2)[260]  = (float(*)[260])(smem + SM_SY2);
    float* scs = (float*)(smem + SM_SCS);
    float* ssn = (float*)(smem + SM_SSN);
    u32*   swp = (u32*)(smem + SM_SWP);

    int tid = threadIdx.x;
    int b = blockIdx.x >> 6, tile = blockIdx.x & 63;
    int y0 = tile << 2;                              // 4 out rows y0..y0+3

    // ---------------- phase 1: staging ----------------
    {   // sf: 51.2KB filtered sinogram for batch b
        const float4* s4 = (const float4*)(ws + OFF_FILT + b * (NANG * 256));
        float4* d4 = (float4*)sf;
        for (int idx = tid; idx < NANG * 64; idx += 512) d4[idx] = s4[idx];
    }
    if (tid < NANG) {
        float a_ = angles[tid];
        scs[tid] = cosf(a_); ssn[tid] = sinf(a_);
    }
    if (tid < 144) {   // w3 packed bf16 ch-pairs [t][kd]
        int t = tid >> 4, kd = tid & 15;
        swp[tid] = (u32)f2bf(w3[(2 * kd) * 9 + t]) | ((u32)f2bf(w3[(2 * kd + 1) * 9 + t]) << 16);
    }
    if (tid < 40) {    // supd halo cols (img -2,-1,256,257) = idx 0,1,258,259
        int r = tid >> 2, c4 = tid & 3;
        supd[r][(c4 < 2) ? c4 : (c4 + 256)] = 0.0f;
    }
    // sy2: y_concat rows y0-3..y0+6, col idx = img+2, zero-padded
    for (int idx = tid; idx < 10 * 260; idx += 512) {
        int r = idx / 260, c = idx - r * 260;
        int iy = y0 - 3 + r, ix = c - 2;
        sy2[r][c] = ((unsigned)iy < 256u && (unsigned)ix < 256u)
                        ? yconc[b * PIX + iy * 256 + ix] : 0.0f;
    }
    __syncthreads();

    // ------------- phase 2: backproject 10 rows (y0-3..y0+6) -------------
    {
        int j = tid & 255, r0 = tid >> 8;     // rows r0+2k, k=0..4
        float xx = (float)j - 127.5f;
        float yyb = (float)(y0 - 3 + r0) - 127.5f;
        float ac0 = 0.f, ac1 = 0.f, ac2 = 0.f, ac3 = 0.f, ac4 = 0.f;
        #pragma unroll 2
        for (int a = 0; a < NANG; ++a) {
            float cs = scs[a], sn = ssn[a];
            float d2 = sn + sn;
            float f0 = xx * cs + yyb * sn + 127.5f;
            float f1 = f0 + d2, f2 = f1 + d2, f3 = f2 + d2, f4 = f3 + d2;
            #define BPSAMP(ff, accv) { \
                float fl = floorf(ff); int i0 = (int)fl; \
                i0 = min(max(i0, 0), 254); \
                float wq = ff - (float)i0; \
                float v = sf[a * 256 + i0] * (1.0f - wq) + sf[a * 256 + i0 + 1] * wq; \
                accv += (ff >= 0.0f && ff <= 255.0f) ? v : 0.0f; }
            BPSAMP(f0, ac0) BPSAMP(f1, ac1) BPSAMP(f2, ac2) BPSAMP(f3, ac3) BPSAMP(f4, ac4)
            #undef BPSAMP
        }
        float step = stepp[0];
        float accs[5] = {ac0, ac1, ac2, ac3, ac4};
        #pragma unroll
        for (int k = 0; k < 5; ++k) {
            int lr = r0 + 2 * k;
            int iy = y0 - 3 + lr;
            float val = 0.0f;
            if ((unsigned)iy < 256u) {
                float yy = (float)iy - 127.5f;
                float mk = (xx * xx + yy * yy <= 16384.0f) ? 1.0f : 0.0f;
                val = yprev[b * PIX + iy * 256 + j] + step * accs[k] * mk;
                if ((unsigned)(iy - y0) < 4u)
                    dout[NPIX + b * PIX + iy * 256 + j] = val;   // second output
            }
            supd[lr][j + 2] = val;
        }
    }
    __syncthreads();   // supd done; sf dead (h1/h2 overwrite it)

    int wv = tid >> 6, lane = tid & 63;
    int m = lane & 15, quad = lane >> 4;
    float bias0 = b2[m], bias1 = b2[m + 16];
    const u16* __restrict__ w2bf = (const u16*)(ws + OFF_W2BF);

    // ---------------- phase 3: four x-quarters ----------------
    #pragma unroll 1
    for (int xq = 0; xq < 4; ++xq) {
        int xbase = xq * 64;
        // ---- conv1: h1 rows y0-2..y0+5 (8), cols L=0..81 <-> px P=xbase-9+L
        {
            int oc0 = wv * 4;
            float W[72];
            const float4* wsrc = (const float4*)(w1 + oc0 * 18);
            #pragma unroll
            for (int i = 0; i < 18; ++i) ((float4*)W)[i] = wsrc[i];
            float bb0 = b1[oc0], bb1 = b1[oc0 + 1], bb2 = b1[oc0 + 2], bb3 = b1[oc0 + 3];
            u16* hp = h1 + wv * H1PLANE;
            #pragma unroll
            for (int it = 0; it < 6; ++it) {
                int idx = it * 64 + lane;            // 328 items: 8 rows x 41 pairs
                if (idx < 328) {
                    int lr = idx / 41, pp = idx - lr * 41;
                    int P = xbase - 9 + 2 * pp;      // odd; pair = (P, P+1)
                    int ir = y0 - 2 + lr;            // image row of h1 output
                    int cgb = P + 1;                 // even; window idx cgb..cgb+3
                    cgb = min(max(cgb, 0), 256);     // clamp (OOR px zeroed below)
                    float a00 = bb0, a01 = bb1, a02 = bb2, a03 = bb3;
                    float a10 = bb0, a11 = bb1, a12 = bb2, a13 = bb3;
                    #pragma unroll
                    for (int ky = 0; ky < 3; ++ky) {
                        float2 ua = *(const float2*)&supd[lr + ky][cgb];
                        float2 ub = *(const float2*)&supd[lr + ky][cgb + 2];
                        float2 ca = *(const float2*)&sy2[lr + ky][cgb];
                        float2 cb2 = *(const float2*)&sy2[lr + ky][cgb + 2];
                        float u[4]  = {ua.x, ua.y, ub.x, ub.y};
                        float c6[4] = {ca.x, ca.y, cb2.x, cb2.y};
                        #pragma unroll
                        for (int kx = 0; kx < 3; ++kx) {
                            int t = ky * 3 + kx;
                            float u0 = u[kx],     c0 = c6[kx];
                            float u1 = u[kx + 1], c1 = c6[kx + 1];
                            a00 += u0 * W[t]      + c0 * W[9 + t];
                            a01 += u0 * W[18 + t] + c0 * W[27 + t];
                            a02 += u0 * W[36 + t] + c0 * W[45 + t];
                            a03 += u0 * W[54 + t] + c0 * W[63 + t];
                            a10 += u1 * W[t]      + c1 * W[9 + t];
                            a11 += u1 * W[18 + t] + c1 * W[27 + t];
                            a12 += u1 * W[36 + t] + c1 * W[45 + t];
                            a13 += u1 * W[54 + t] + c1 * W[63 + t];
                        }
                    }
                    bool rowOK = (unsigned)ir < 256u;
                    bool v0 = rowOK && ((unsigned)P < 256u);
                    bool v1 = rowOK && ((unsigned)(P + 1) < 256u);
                    u32 q00 = 0, q01 = 0, q10 = 0, q11 = 0;
                    if (v0) {
                        q00 = (u32)f2bf(fmaxf(a00, 0.f)) | ((u32)f2bf(fmaxf(a01, 0.f)) << 16);
                        q01 = (u32)f2bf(fmaxf(a02, 0.f)) | ((u32)f2bf(fmaxf(a03, 0.f)) << 16);
                    }
                    if (v1) {
                        q10 = (u32)f2bf(fmaxf(a10, 0.f)) | ((u32)f2bf(fmaxf(a11, 0.f)) << 16);
                        q11 = (u32)f2bf(fmaxf(a12, 0.f)) | ((u32)f2bf(fmaxf(a13, 0.f)) << 16);
                    }
                    // one contiguous 16B store (conflict-free)
                    uint4* op = (uint4*)(hp + (lr * H1COLS + 2 * pp) * 4);
                    *op = make_uint4(q00, q01, q10, q11);
                }
            }
        }
        __syncthreads();

        // ---- conv2 MFMA: 30 tiles (6 h2 rows x 5 px-tiles of 16) over 8 waves
        {
            bfrag Bf[9][2];
            #pragma unroll
            for (int t = 0; t < 9; ++t) {
                const u16* wp = w2bf + t * 1024 + m * 32 + quad * 8;
                Bf[t][0] = *(const bfrag*)(wp);
                Bf[t][1] = *(const bfrag*)(wp + 16 * 32);
            }
            #pragma unroll
            for (int k = 0; k < 4; ++k) {
                int tl = wv + (k << 3);
                if (tl < 30) {
                    int ridx = tl / 5, pt = tl - ridx * 5;
                    int hy = y0 - 1 + ridx;
                    bool hyOK = (unsigned)hy < 256u;
                    int Lb = 16 * pt + m;
                    const u16* qp = h1 + quad * (2 * H1PLANE);
                    #define LDF(row, L, dst) { \
                        const u16* p0_ = qp + ((row) * H1COLS + (L)) * 4; \
                        uint2 lo_ = *(const uint2*)p0_; \
                        uint2 hi_ = *(const uint2*)(p0_ + H1PLANE); \
                        ((uint2*)&dst)[0] = lo_; ((uint2*)&dst)[1] = hi_; }
                    bfrag A0[3], A1[3];
                    #pragma unroll
                    for (int tx = 0; tx < 3; ++tx) LDF(ridx + 0, Lb + tx, A0[tx])
                    #pragma unroll
                    for (int tx = 0; tx < 3; ++tx) LDF(ridx + 1, Lb + tx, A1[tx])
                    ffrag c0 = {0.f, 0.f, 0.f, 0.f}, c1 = {0.f, 0.f, 0.f, 0.f};
                    #pragma unroll
                    for (int tx = 0; tx < 3; ++tx) {
                        c0 = __builtin_amdgcn_mfma_f32_16x16x32_bf16(A0[tx], Bf[tx][0], c0, 0, 0, 0);
                        c1 = __builtin_amdgcn_mfma_f32_16x16x32_bf16(A0[tx], Bf[tx][1], c1, 0, 0, 0);
                    }
                    #pragma unroll
                    for (int tx = 0; tx < 3; ++tx) LDF(ridx + 2, Lb + tx, A0[tx])
                    #pragma unroll
                    for (int tx = 0; tx < 3; ++tx) {
                        c0 = __builtin_amdgcn_mfma_f32_16x16x32_bf16(A1[tx], Bf[3 + tx][0], c0, 0, 0, 0);
                        c1 = __builtin_amdgcn_mfma_f32_16x16x32_bf16(A1[tx], Bf[3 + tx][1], c1, 0, 0, 0);
                    }
                    #pragma unroll
                    for (int tx = 0; tx < 3; ++tx) {
                        c0 = __builtin_amdgcn_mfma_f32_16x16x32_bf16(A0[tx], Bf[6 + tx][0], c0, 0, 0, 0);
                        c1 = __builtin_amdgcn_mfma_f32_16x16x32_bf16(A0[tx], Bf[6 + tx][1], c1, 0, 0, 0);
                    }
                    #undef LDF
                    #pragma unroll
                    for (int r = 0; r < 4; ++r) {
                        int pl = 16 * pt + quad * 4 + r;       // h2 local col
                        int pimg = xbase - 8 + pl;
                        bool ok = hyOK && ((unsigned)pimg < 256u);
                        float f0 = ok ? fmaxf(c0[r] + bias0, 0.0f) : 0.0f;
                        float f1 = ok ? fmaxf(c1[r] + bias1, 0.0f) : 0.0f;
                        u16* op = sh2 + (ridx * H2COLS + pl) * H2PITCH;
                        op[m]      = f2bf(f0);
                        op[m + 16] = f2bf(f1);
                    }
                }
            }
        }
        __syncthreads();

        // ---- conv3 (32->1): one px per thread (256 px), stride-1 slots ----
        if (tid < 256) {
            int rr = tid >> 6, xl = tid & 63;
            int oy = y0 + rr;
            float acc = b3[0];
            #pragma unroll
            for (int ky = 0; ky < 3; ++ky) {
                #pragma unroll
                for (int cx = 0; cx < 3; ++cx) {
                    int t = ky * 3 + cx;
                    const uint2* q2 = (const uint2*)(l32h2 + ((rr + ky) * H2COLS + xl + cx + 7) * 18);
                    const uint2* wp = (const uint2*)(swp + t * 16);
                    #pragma unroll
                    for (int kd = 0; kd < 8; ++kd) {
                        uint2 hv = q2[kd];
                        uint2 wvv = wp[kd];
                        acc += __uint_as_float(hv.x << 16) * __uint_as_float(wvv.x << 16)
                             + __uint_as_float(hv.x & 0xffff0000u) * __uint_as_float(wvv.x & 0xffff0000u)
                             + __uint_as_float(hv.y << 16) * __uint_as_float(wvv.y << 16)
                             + __uint_as_float(hv.y & 0xffff0000u) * __uint_as_float(wvv.y & 0xffff0000u);
                    }
                }
            }
            dout[b * PIX + oy * 256 + xbase + xl] = acc;   // first output
        }
        // no barrier: next conv1 writes h1 (readers done before conv2 barrier);
        // next conv2's h2 writes are behind the conv1 barrier.
    }
}

extern "C" void kernel_launch(void* const* d_in, const int* in_sizes, int n_in,
                              void* d_out, int out_size, void* d_ws, size_t ws_size,
                              hipStream_t stream) {
    const float* xsino  = (const float*)d_in[0];
    const float* yprev  = (const float*)d_in[1];
    const float* yconc  = (const float*)d_in[2];
    const float* angles = (const float*)d_in[3];
    const float* stepp  = (const float*)d_in[4];
    const float* w1 = (const float*)d_in[5];
    const float* b1 = (const float*)d_in[6];
    const float* w2 = (const float*)d_in[7];
    const float* b2 = (const float*)d_in[8];
    const float* w3 = (const float*)d_in[9];
    const float* b3 = (const float*)d_in[10];
    float* out = (float*)d_out;
    float* ws  = (float*)d_ws;

    k_A<<<209, 1024, 0, stream>>>(angles, yprev, xsino, w2, ws);
    k_BC<<<BATCH * 64, 512, 0, stream>>>(angles, yprev, yconc, stepp, w1, b1,
                                         b2, w3, b3, ws, out);
}